// Round 5
// baseline (720.881 us; speedup 1.0000x reference)
//
#include <hip/hip_runtime.h>

// QuantLinear W4A32 — round 5: full pre-dequant.
//  * prep_x: x fp32 -> f16, tile-padded (128x40 halves, 10240B) in ws.
//  * prep_w: 4-bit W -> f16 (magic-trick dequant), tile-padded
//    (256x40 halves, 20480B per (nt,kt) tile) in ws.
//  * qgemm_pre: pure DMA-fed f16 GEMM, m97 2-barrier structure, 128x256 tile,
//    512 threads (2x4 waves), BK=32, zero staging VALU.
// Fallbacks by ws_size: round-4 fused-B path, then round-3 fully-fused path.

#define BK 32
#define LDK 40             // padded row stride in halves (80B, 16B-multiple)
#define TILE_BYTES 10240   // A tile: 128 * LDK * 2
#define WTILE_BYTES 20480  // B tile: 256 * LDK * 2

typedef _Float16 v8h __attribute__((ext_vector_type(8)));
typedef _Float16 half2v __attribute__((ext_vector_type(2)));
typedef float v4f __attribute__((ext_vector_type(4)));

__device__ __forceinline__ unsigned pkrtz_u32(float a, float b) {
  return __builtin_bit_cast(unsigned, __builtin_amdgcn_cvt_pkrtz(a, b));
}

__device__ __forceinline__ void load_lds_16B(const void* g, void* l) {
  __builtin_amdgcn_global_load_lds(
      (const __attribute__((address_space(1))) unsigned*)g,
      (__attribute__((address_space(3))) unsigned*)l, 16, 0, 0);
}

// ---------------- prep_x: fp32 -> f16 tiled-padded ----------------
// grid (K/32, M/128), 256 threads.
__global__ __launch_bounds__(256)
void prep_x(const float* __restrict__ x, unsigned short* __restrict__ xt, int K) {
  const int kt = blockIdx.x, mt = blockIdx.y;
  const int t = threadIdx.x;
  const int row = t >> 1, half = t & 1;
  const float* src = x + (size_t)(mt * 128 + row) * K + kt * 32 + half * 16;
  const float4 v0 = ((const float4*)src)[0];
  const float4 v1 = ((const float4*)src)[1];
  const float4 v2 = ((const float4*)src)[2];
  const float4 v3 = ((const float4*)src)[3];
  uint4 o0, o1;
  o0.x = pkrtz_u32(v0.x, v0.y); o0.y = pkrtz_u32(v0.z, v0.w);
  o0.z = pkrtz_u32(v1.x, v1.y); o0.w = pkrtz_u32(v1.z, v1.w);
  o1.x = pkrtz_u32(v2.x, v2.y); o1.y = pkrtz_u32(v2.z, v2.w);
  o1.z = pkrtz_u32(v3.x, v3.y); o1.w = pkrtz_u32(v3.z, v3.w);
  unsigned short* dst =
      xt + (size_t)(mt * (K / 32) + kt) * (TILE_BYTES / 2) + row * LDK + half * 16;
  ((uint4*)dst)[0] = o0;
  ((uint4*)(dst + 8))[0] = o1;
}

// ---------------- prep_w: 4-bit -> f16 tiled-padded ----------------
// grid (N/256, K/32), 256 threads; thread = one n-column, 32 k-values.
__global__ __launch_bounds__(256)
void prep_w(const unsigned* __restrict__ qweight,
            const unsigned* __restrict__ qzeros,
            const float* __restrict__ scales,
            unsigned short* __restrict__ wt, int N, int K) {
  const int nt = blockIdx.x, kt = blockIdx.y;
  const int n_loc = threadIdx.x;
  const int gn = nt * 256 + n_loc;
  const int g = kt >> 2;  // group of this 32-k slab
  const unsigned zp = qzeros[(size_t)g * (N >> 3) + (gn >> 3)];
  const float s = scales[(size_t)g * N + gn];
  const unsigned z = (zp >> ((gn & 7) * 4)) & 15u;
  const unsigned hz_u = 0x64006400u | z | (z << 16);
  const half2v hz2 = __builtin_bit_cast(half2v, hz_u);
  const half2v hs2 = __builtin_bit_cast(half2v, pkrtz_u32(s, s));
  unsigned short* dst =
      wt + (size_t)(nt * (K / 32) + kt) * (WTILE_BYTES / 2) + n_loc * LDK;
#pragma unroll
  for (int kr = 0; kr < 4; ++kr) {
    const unsigned qv = qweight[(size_t)(kt * 4 + kr) * N + gn];
    uint4 wv;
    unsigned* wp = (unsigned*)&wv;
#pragma unroll
    for (int j = 0; j < 4; ++j) {
      const unsigned byte = qv >> (8 * j);
      const unsigned pq = 0x64006400u | (byte & 0xFu) | ((byte & 0xF0u) << 12);
      const half2v w2 = (__builtin_bit_cast(half2v, pq) - hz2) * hs2;
      wp[j] = __builtin_bit_cast(unsigned, w2);
    }
    *(uint4*)(dst + kr * 8) = wv;
  }
}

// ---------------- main: pure DMA GEMM, 128x256 tile ----------------
__global__ __launch_bounds__(512, 4)
void qgemm_pre(const unsigned short* __restrict__ xt,
               const unsigned short* __restrict__ wt,
               float* __restrict__ out, int M, int N, int K) {
  __shared__ __align__(16) short As[128][LDK];
  __shared__ __align__(16) short Bs[256][LDK];

  const int tid = threadIdx.x;
  const int lane = tid & 63;
  const int wid = tid >> 6;  // 8 waves
  const int nt = blockIdx.x, mt = blockIdx.y;
  const int n0 = nt * 256, m0 = mt * 128;
  const int wm = (wid >> 2) * 64;
  const int wn = (wid & 3) * 64;
  const int lr = lane & 15;
  const int lk = (lane >> 4) * 8;

  const int NT = K / BK;  // 128
  const char* ga = (const char*)xt + (size_t)mt * NT * TILE_BYTES +
                   wid * 1024 + lane * 16;
  const char* gb = (const char*)wt + (size_t)nt * NT * WTILE_BYTES +
                   wid * 1024 + lane * 16;
  char* la = ((char*)&As[0][0]) + wid * 1024;  // HW adds lane*16
  char* lb = ((char*)&Bs[0][0]) + wid * 1024;

  v4f acc[4][4] = {};

#pragma unroll 2
  for (int t = 0; t < NT; ++t) {
    // ---- A: 10KB in 1KB wave-chunks ----
    load_lds_16B(ga, la);
    if (wid < 2) load_lds_16B(ga + 8 * 1024, la + 8 * 1024);
    // ---- B: 20KB in 1KB wave-chunks ----
    load_lds_16B(gb, lb);
    load_lds_16B(gb + 8 * 1024, lb + 8 * 1024);
    if (wid < 4) load_lds_16B(gb + 16 * 1024, lb + 16 * 1024);

    __syncthreads();  // drains DMA (vmcnt) for all waves

    v8h af[4], bfr[4];
#pragma unroll
    for (int i = 0; i < 4; ++i) {
      af[i] = *(const v8h*)(&As[wm + i * 16 + lr][lk]);   // ds_read_b128
      bfr[i] = *(const v8h*)(&Bs[wn + i * 16 + lr][lk]);  // ds_read_b128
    }
#pragma unroll
    for (int mi = 0; mi < 4; ++mi) {
#pragma unroll
      for (int ni = 0; ni < 4; ++ni) {
        acc[mi][ni] = __builtin_amdgcn_mfma_f32_16x16x32_f16(
            af[mi], bfr[ni], acc[mi][ni], 0, 0, 0);
      }
    }

    __syncthreads();

    ga += TILE_BYTES;
    gb += WTILE_BYTES;
  }

  // ---- epilogue: C/D layout col=lane&15, row=(lane>>4)*4+reg ----
#pragma unroll
  for (int mi = 0; mi < 4; ++mi) {
#pragma unroll
    for (int ni = 0; ni < 4; ++ni) {
#pragma unroll
      for (int r = 0; r < 4; ++r) {
        const int row = m0 + wm + mi * 16 + (lane >> 4) * 4 + r;
        const int col = n0 + wn + ni * 16 + lr;
        out[(size_t)row * N + col] = acc[mi][ni][r];
      }
    }
  }
}

// ---------------- fallback 1: round-4 (A DMA, B fused dequant) ----------------
__global__ __launch_bounds__(512, 4)
void qgemm_dma(const unsigned short* __restrict__ xt,
               const unsigned* __restrict__ qweight,
               const unsigned* __restrict__ qzeros,
               const float* __restrict__ scales,
               float* __restrict__ out, int M, int N, int K) {
  __shared__ __align__(16) short As[128][LDK];
  __shared__ __align__(16) short Bs[256][LDK];

  const int tid = threadIdx.x;
  const int lane = tid & 63;
  const int wid = tid >> 6;
  const int n0 = blockIdx.x * 256;
  const int m0 = blockIdx.y * 128;
  const int mt = blockIdx.y;
  const int wm = (wid >> 2) * 64;
  const int wn = (wid & 3) * 64;
  const int lr = lane & 15;
  const int lk = (lane >> 4) * 8;

  const int b_n = tid & 255;
  const int b_kr0 = tid >> 8;
  const int gn = n0 + b_n;
  const unsigned* qwb = qweight + (size_t)b_kr0 * N + gn;

  const char* xt_b = (const char*)xt;
  const int NT = K / BK;

  v4f acc[4][4] = {};

  unsigned b0c, b1c, zpc;
  float scc;
  auto load_b = [&](int t, unsigned& b0, unsigned& b1, unsigned& zp, float& sc) {
    const int kk = t * BK;
    const size_t qoff = (size_t)(kk >> 3) * N;
    b0 = qwb[qoff];
    b1 = qwb[qoff + 2 * (size_t)N];
    const int g = kk >> 7;
    zp = qzeros[(size_t)g * (N >> 3) + (gn >> 3)];
    sc = scales[(size_t)g * N + gn];
  };
  load_b(0, b0c, b1c, zpc, scc);

#pragma unroll 2
  for (int t = 0; t < NT; ++t) {
    {
      const char* g = xt_b + (size_t)(mt * NT + t) * TILE_BYTES +
                      (size_t)wid * 1024 + (size_t)lane * 16;
      char* l = ((char*)&As[0][0]) + wid * 1024;
      load_lds_16B(g, l);
      if (wid < 2) load_lds_16B(g + 8 * 1024, l + 8 * 1024);
    }
    {
      const unsigned z = (zpc >> ((gn & 7) * 4)) & 15u;
      const unsigned hz_u = 0x64006400u | z | (z << 16);
      const half2v hz2 = __builtin_bit_cast(half2v, hz_u);
      const half2v hs2 = __builtin_bit_cast(half2v, pkrtz_u32(scc, scc));
      const unsigned qvs[2] = {b0c, b1c};
#pragma unroll
      for (int q = 0; q < 2; ++q) {
        const int kr = b_kr0 + q * 2;
        const unsigned qv = qvs[q];
        uint4 wv;
        unsigned* wp = (unsigned*)&wv;
#pragma unroll
        for (int j = 0; j < 4; ++j) {
          const unsigned byte = qv >> (8 * j);
          const unsigned pq = 0x64006400u | (byte & 0xFu) | ((byte & 0xF0u) << 12);
          const half2v w2 = (__builtin_bit_cast(half2v, pq) - hz2) * hs2;
          wp[j] = __builtin_bit_cast(unsigned, w2);
        }
        *(uint4*)(&Bs[b_n][kr * 8]) = wv;
      }
    }

    __syncthreads();

    unsigned b0n, b1n, zpn;
    float scn;
    const int tn = (t + 1 < NT) ? (t + 1) : t;
    load_b(tn, b0n, b1n, zpn, scn);

    v8h af[4], bfr[4];
#pragma unroll
    for (int i = 0; i < 4; ++i) {
      af[i] = *(const v8h*)(&As[wm + i * 16 + lr][lk]);
      bfr[i] = *(const v8h*)(&Bs[wn + i * 16 + lr][lk]);
    }
#pragma unroll
    for (int mi = 0; mi < 4; ++mi) {
#pragma unroll
      for (int ni = 0; ni < 4; ++ni) {
        acc[mi][ni] = __builtin_amdgcn_mfma_f32_16x16x32_f16(
            af[mi], bfr[ni], acc[mi][ni], 0, 0, 0);
      }
    }

    __syncthreads();

    b0c = b0n; b1c = b1n; zpc = zpn; scc = scn;
  }

#pragma unroll
  for (int mi = 0; mi < 4; ++mi) {
#pragma unroll
    for (int ni = 0; ni < 4; ++ni) {
#pragma unroll
      for (int r = 0; r < 4; ++r) {
        const int row = m0 + wm + mi * 16 + (lane >> 4) * 4 + r;
        const int col = n0 + wn + ni * 16 + lr;
        out[(size_t)row * N + col] = acc[mi][ni][r];
      }
    }
  }
}

// ---------------- fallback 2: round-3 fully fused (128x128) ----------------
__global__ __launch_bounds__(256, 2)
void qgemm_fused(const float* __restrict__ x,
                 const unsigned* __restrict__ qweight,
                 const unsigned* __restrict__ qzeros,
                 const float* __restrict__ scales,
                 float* __restrict__ out, int M, int N, int K) {
  __shared__ short As[128][LDK];
  __shared__ short Bs[128][LDK];

  const int tid = threadIdx.x;
  const int lane = tid & 63;
  const int wid = tid >> 6;
  const int n0 = blockIdx.x * 128;
  const int m0 = blockIdx.y * 128;
  const int wm = (wid >> 1) * 64;
  const int wn = (wid & 1) * 64;
  const int lr = lane & 15;
  const int lk = (lane >> 4) * 8;

  const int a_row = tid >> 3;
  const int a_col = (tid & 7) * 4;
  const int b_n = tid & 127;
  const int b_kr0 = tid >> 7;
  const int gn = n0 + b_n;

  const float* xb = x + (size_t)(m0 + a_row) * K + a_col;
  const unsigned* qwb = qweight + (size_t)b_kr0 * N + gn;

  v4f acc[4][4] = {};
  const int NT = K / BK;

  float4 axc[4];
  unsigned b0c, b1c, zpc;
  float scc;

  auto load_step = [&](int t, float4 ax[4], unsigned& b0, unsigned& b1,
                       unsigned& zp, float& sc) {
    const int kk = t * BK;
#pragma unroll
    for (int p = 0; p < 4; ++p)
      ax[p] = *(const float4*)(xb + (size_t)(p * 32) * K + kk);
    const size_t qoff = (size_t)(kk >> 3) * N;
    b0 = qwb[qoff];
    b1 = qwb[qoff + 2 * (size_t)N];
    const int g = kk >> 7;
    zp = qzeros[(size_t)g * (N >> 3) + (gn >> 3)];
    sc = scales[(size_t)g * N + gn];
  };

  load_step(0, axc, b0c, b1c, zpc, scc);

#pragma unroll 2
  for (int t = 0; t < NT; ++t) {
    const unsigned z = (zpc >> ((gn & 7) * 4)) & 15u;
    const unsigned hz_u = 0x64006400u | z | (z << 16);
    const half2v hz2 = __builtin_bit_cast(half2v, hz_u);
    const half2v hs2 = __builtin_bit_cast(half2v, pkrtz_u32(scc, scc));

#pragma unroll
    for (int p = 0; p < 4; ++p) {
      const int row = p * 32 + a_row;
      uint2 pv;
      pv.x = pkrtz_u32(axc[p].x, axc[p].y);
      pv.y = pkrtz_u32(axc[p].z, axc[p].w);
      *(uint2*)(&As[row][a_col]) = pv;
    }
    {
      const unsigned qvs[2] = {b0c, b1c};
#pragma unroll
      for (int q = 0; q < 2; ++q) {
        const int kr = b_kr0 + q * 2;
        const unsigned qv = qvs[q];
        uint4 wv;
        unsigned* wp = (unsigned*)&wv;
#pragma unroll
        for (int j = 0; j < 4; ++j) {
          const unsigned byte = qv >> (8 * j);
          const unsigned pq = 0x64006400u | (byte & 0xFu) | ((byte & 0xF0u) << 12);
          const half2v w2 = (__builtin_bit_cast(half2v, pq) - hz2) * hs2;
          wp[j] = __builtin_bit_cast(unsigned, w2);
        }
        *(uint4*)(&Bs[b_n][kr * 8]) = wv;
      }
    }

    __syncthreads();

    float4 axn[4];
    unsigned b0n, b1n, zpn;
    float scn;
    const int tn = (t + 1 < NT) ? (t + 1) : t;
    load_step(tn, axn, b0n, b1n, zpn, scn);

    v8h af[4], bfr[4];
#pragma unroll
    for (int i = 0; i < 4; ++i) {
      af[i] = *(const v8h*)(&As[wm + i * 16 + lr][lk]);
      bfr[i] = *(const v8h*)(&Bs[wn + i * 16 + lr][lk]);
    }
#pragma unroll
    for (int mi = 0; mi < 4; ++mi) {
#pragma unroll
      for (int ni = 0; ni < 4; ++ni) {
        acc[mi][ni] = __builtin_amdgcn_mfma_f32_16x16x32_f16(
            af[mi], bfr[ni], acc[mi][ni], 0, 0, 0);
      }
    }

    __syncthreads();

#pragma unroll
    for (int p = 0; p < 4; ++p) axc[p] = axn[p];
    b0c = b0n; b1c = b1n; zpc = zpn; scc = scn;
  }

#pragma unroll
  for (int mi = 0; mi < 4; ++mi) {
#pragma unroll
    for (int ni = 0; ni < 4; ++ni) {
#pragma unroll
      for (int r = 0; r < 4; ++r) {
        const int row = m0 + wm + mi * 16 + (lane >> 4) * 4 + r;
        const int col = n0 + wn + ni * 16 + lr;
        out[(size_t)row * N + col] = acc[mi][ni][r];
      }
    }
  }
}

extern "C" void kernel_launch(void* const* d_in, const int* in_sizes, int n_in,
                              void* d_out, int out_size, void* d_ws, size_t ws_size,
                              hipStream_t stream) {
  const float* x = (const float*)d_in[0];
  const unsigned* qweight = (const unsigned*)d_in[1];
  const unsigned* qzeros = (const unsigned*)d_in[2];
  const float* scales = (const float*)d_in[3];
  float* out = (float*)d_out;

  const int K = 4096;
  const int N = 11008;
  const int M = in_sizes[0] / K;  // 4096

  const size_t A_BYTES = (size_t)(M / 128) * (K / 32) * TILE_BYTES;   // 41.9 MB
  const size_t W_BYTES = (size_t)(N / 256) * (K / 32) * WTILE_BYTES;  // 112.7 MB

  if (ws_size >= A_BYTES + W_BYTES) {
    unsigned short* xt = (unsigned short*)d_ws;
    unsigned short* wtp = (unsigned short*)((char*)d_ws + A_BYTES);
    prep_x<<<dim3(K / 32, M / 128), 256, 0, stream>>>(x, xt, K);
    prep_w<<<dim3(N / 256, K / 32), 256, 0, stream>>>(qweight, qzeros, scales, wtp, N, K);
    qgemm_pre<<<dim3(N / 256, M / 128), 512, 0, stream>>>(xt, wtp, out, M, N, K);
  } else if (ws_size >= A_BYTES) {
    unsigned short* xt = (unsigned short*)d_ws;
    prep_x<<<dim3(K / 32, M / 128), 256, 0, stream>>>(x, xt, K);
    qgemm_dma<<<dim3(N / 256, M / 128), 512, 0, stream>>>(xt, qweight, qzeros, scales,
                                                          out, M, N, K);
  } else {
    qgemm_fused<<<dim3(N / 128, M / 128), 256, 0, stream>>>(x, qweight, qzeros, scales,
                                                            out, M, N, K);
  }
}

// Round 6
// 660.248 us; speedup vs baseline: 1.0918x; 1.0918x over previous
//
#include <hip/hip_runtime.h>

// QuantLinear W4A32 — round 6: round-5 + L3-locality grid swap + coalesced preps.
//  * prep_x / prep_w: chunk-indexed, stores are contiguous 16B/lane (1KB/wave).
//  * qgemm_pre: pure DMA-fed f16 GEMM, 128x256 tile, 512 threads, BK=32;
//    grid is (m-tiles fastest) so concurrent blocks reuse the same W n-columns
//    out of L3 instead of thrashing it.
// Fallbacks by ws_size: round-4 fused-B path, then round-3 fully-fused path.

#define BK 32
#define LDK 40             // padded row stride in halves (80B, 16B-multiple)
#define TILE_BYTES 10240   // A tile: 128 * LDK * 2
#define WTILE_BYTES 20480  // B tile: 256 * LDK * 2

typedef _Float16 v8h __attribute__((ext_vector_type(8)));
typedef _Float16 half2v __attribute__((ext_vector_type(2)));
typedef float v4f __attribute__((ext_vector_type(4)));

__device__ __forceinline__ unsigned pkrtz_u32(float a, float b) {
  return __builtin_bit_cast(unsigned, __builtin_amdgcn_cvt_pkrtz(a, b));
}

__device__ __forceinline__ void load_lds_16B(const void* g, void* l) {
  __builtin_amdgcn_global_load_lds(
      (const __attribute__((address_space(1))) unsigned*)g,
      (__attribute__((address_space(3))) unsigned*)l, 16, 0, 0);
}

// ---------------- prep_x: fp32 -> f16 tiled-padded, coalesced stores ----------
// grid (K/32, M/128), 320 threads; 640 16B-chunks per tile, 2 per thread.
// chunk c -> row r=c/5, slot j=c%5 (j==4 is padding).
__global__ __launch_bounds__(320)
void prep_x(const float* __restrict__ x, unsigned short* __restrict__ xt, int K) {
  const int kt = blockIdx.x, mt = blockIdx.y;
  unsigned short* tile = xt + (size_t)(mt * (K / 32) + kt) * (TILE_BYTES / 2);
#pragma unroll
  for (int p = 0; p < 2; ++p) {
    const int c = threadIdx.x + p * 320;
    const int r = c / 5, j = c - r * 5;
    uint4 o = {0u, 0u, 0u, 0u};
    if (j < 4) {
      const float* src = x + (size_t)(mt * 128 + r) * K + kt * 32 + j * 8;
      const float4 v0 = ((const float4*)src)[0];
      const float4 v1 = ((const float4*)src)[1];
      o.x = pkrtz_u32(v0.x, v0.y); o.y = pkrtz_u32(v0.z, v0.w);
      o.z = pkrtz_u32(v1.x, v1.y); o.w = pkrtz_u32(v1.z, v1.w);
    }
    *(uint4*)((char*)tile + (size_t)c * 16) = o;  // coalesced
  }
}

// ---------------- prep_w: 4-bit -> f16 tiled-padded, coalesced stores --------
// grid (N/256, K/32), 256 threads; 1280 chunks per tile, 5 per thread.
// chunk c -> col n=c/5, slot j=c%5; one qweight word -> one 16B chunk.
__global__ __launch_bounds__(256)
void prep_w(const unsigned* __restrict__ qweight,
            const unsigned* __restrict__ qzeros,
            const float* __restrict__ scales,
            unsigned short* __restrict__ wt, int N, int K) {
  const int nt = blockIdx.x, kt = blockIdx.y;
  const int g = kt >> 2;
  unsigned short* tile = wt + (size_t)(nt * (K / 32) + kt) * (WTILE_BYTES / 2);
#pragma unroll
  for (int p = 0; p < 5; ++p) {
    const int c = threadIdx.x + p * 256;
    const int n = c / 5, j = c - n * 5;
    const int gn = nt * 256 + n;
    uint4 o = {0u, 0u, 0u, 0u};
    if (j < 4) {
      const unsigned zp = qzeros[(size_t)g * (N >> 3) + (gn >> 3)];
      const float s = scales[(size_t)g * N + gn];
      const unsigned z = (zp >> ((gn & 7) * 4)) & 15u;
      const unsigned hz_u = 0x64006400u | z | (z << 16);
      const half2v hz2 = __builtin_bit_cast(half2v, hz_u);
      const half2v hs2 = __builtin_bit_cast(half2v, pkrtz_u32(s, s));
      const unsigned qv = qweight[(size_t)(kt * 4 + j) * N + gn];
      unsigned* wp = (unsigned*)&o;
#pragma unroll
      for (int b = 0; b < 4; ++b) {
        const unsigned byte = qv >> (8 * b);
        const unsigned pq = 0x64006400u | (byte & 0xFu) | ((byte & 0xF0u) << 12);
        const half2v w2 = (__builtin_bit_cast(half2v, pq) - hz2) * hs2;
        wp[b] = __builtin_bit_cast(unsigned, w2);
      }
    }
    *(uint4*)((char*)tile + (size_t)c * 16) = o;  // coalesced
  }
}

// ---------------- main: pure DMA GEMM, 128x256 tile, m-fastest grid ----------
__global__ __launch_bounds__(512, 4)
void qgemm_pre(const unsigned short* __restrict__ xt,
               const unsigned short* __restrict__ wt,
               float* __restrict__ out, int M, int N, int K) {
  __shared__ __align__(16) short As[128][LDK];
  __shared__ __align__(16) short Bs[256][LDK];

  const int tid = threadIdx.x;
  const int lane = tid & 63;
  const int wid = tid >> 6;  // 8 waves
  const int mt = blockIdx.x, nt = blockIdx.y;  // m-tiles fastest (L3 reuse of W)
  const int n0 = nt * 256, m0 = mt * 128;
  const int wm = (wid >> 2) * 64;
  const int wn = (wid & 3) * 64;
  const int lr = lane & 15;
  const int lk = (lane >> 4) * 8;

  const int NT = K / BK;  // 128
  const char* ga = (const char*)xt + (size_t)mt * NT * TILE_BYTES +
                   wid * 1024 + lane * 16;
  const char* gb = (const char*)wt + (size_t)nt * NT * WTILE_BYTES +
                   wid * 1024 + lane * 16;
  char* la = ((char*)&As[0][0]) + wid * 1024;  // HW adds lane*16
  char* lb = ((char*)&Bs[0][0]) + wid * 1024;

  v4f acc[4][4] = {};

#pragma unroll 2
  for (int t = 0; t < NT; ++t) {
    // ---- A: 10KB in 1KB wave-chunks ----
    load_lds_16B(ga, la);
    if (wid < 2) load_lds_16B(ga + 8 * 1024, la + 8 * 1024);
    // ---- B: 20KB in 1KB wave-chunks ----
    load_lds_16B(gb, lb);
    load_lds_16B(gb + 8 * 1024, lb + 8 * 1024);
    if (wid < 4) load_lds_16B(gb + 16 * 1024, lb + 16 * 1024);

    __syncthreads();  // drains DMA (vmcnt) for all waves

    v8h af[4], bfr[4];
#pragma unroll
    for (int i = 0; i < 4; ++i) {
      af[i] = *(const v8h*)(&As[wm + i * 16 + lr][lk]);   // ds_read_b128
      bfr[i] = *(const v8h*)(&Bs[wn + i * 16 + lr][lk]);  // ds_read_b128
    }
#pragma unroll
    for (int mi = 0; mi < 4; ++mi) {
#pragma unroll
      for (int ni = 0; ni < 4; ++ni) {
        acc[mi][ni] = __builtin_amdgcn_mfma_f32_16x16x32_f16(
            af[mi], bfr[ni], acc[mi][ni], 0, 0, 0);
      }
    }

    __syncthreads();

    ga += TILE_BYTES;
    gb += WTILE_BYTES;
  }

  // ---- epilogue: C/D layout col=lane&15, row=(lane>>4)*4+reg ----
#pragma unroll
  for (int mi = 0; mi < 4; ++mi) {
#pragma unroll
    for (int ni = 0; ni < 4; ++ni) {
#pragma unroll
      for (int r = 0; r < 4; ++r) {
        const int row = m0 + wm + mi * 16 + (lane >> 4) * 4 + r;
        const int col = n0 + wn + ni * 16 + lr;
        out[(size_t)row * N + col] = acc[mi][ni][r];
      }
    }
  }
}

// ---------------- fallback 1: round-4 (A DMA, B fused dequant) ----------------
__global__ __launch_bounds__(512, 4)
void qgemm_dma(const unsigned short* __restrict__ xt,
               const unsigned* __restrict__ qweight,
               const unsigned* __restrict__ qzeros,
               const float* __restrict__ scales,
               float* __restrict__ out, int M, int N, int K) {
  __shared__ __align__(16) short As[128][LDK];
  __shared__ __align__(16) short Bs[256][LDK];

  const int tid = threadIdx.x;
  const int lane = tid & 63;
  const int wid = tid >> 6;
  const int n0 = blockIdx.x * 256;
  const int m0 = blockIdx.y * 128;
  const int mt = blockIdx.y;
  const int wm = (wid >> 2) * 64;
  const int wn = (wid & 3) * 64;
  const int lr = lane & 15;
  const int lk = (lane >> 4) * 8;

  const int b_n = tid & 255;
  const int b_kr0 = tid >> 8;
  const int gn = n0 + b_n;
  const unsigned* qwb = qweight + (size_t)b_kr0 * N + gn;

  const char* xt_b = (const char*)xt;
  const int NT = K / BK;

  v4f acc[4][4] = {};

  unsigned b0c, b1c, zpc;
  float scc;
  auto load_b = [&](int t, unsigned& b0, unsigned& b1, unsigned& zp, float& sc) {
    const int kk = t * BK;
    const size_t qoff = (size_t)(kk >> 3) * N;
    b0 = qwb[qoff];
    b1 = qwb[qoff + 2 * (size_t)N];
    const int g = kk >> 7;
    zp = qzeros[(size_t)g * (N >> 3) + (gn >> 3)];
    sc = scales[(size_t)g * N + gn];
  };
  load_b(0, b0c, b1c, zpc, scc);

#pragma unroll 2
  for (int t = 0; t < NT; ++t) {
    {
      const char* g = xt_b + (size_t)(mt * NT + t) * TILE_BYTES +
                      (size_t)wid * 1024 + (size_t)lane * 16;
      char* l = ((char*)&As[0][0]) + wid * 1024;
      load_lds_16B(g, l);
      if (wid < 2) load_lds_16B(g + 8 * 1024, l + 8 * 1024);
    }
    {
      const unsigned z = (zpc >> ((gn & 7) * 4)) & 15u;
      const unsigned hz_u = 0x64006400u | z | (z << 16);
      const half2v hz2 = __builtin_bit_cast(half2v, hz_u);
      const half2v hs2 = __builtin_bit_cast(half2v, pkrtz_u32(scc, scc));
      const unsigned qvs[2] = {b0c, b1c};
#pragma unroll
      for (int q = 0; q < 2; ++q) {
        const int kr = b_kr0 + q * 2;
        const unsigned qv = qvs[q];
        uint4 wv;
        unsigned* wp = (unsigned*)&wv;
#pragma unroll
        for (int j = 0; j < 4; ++j) {
          const unsigned byte = qv >> (8 * j);
          const unsigned pq = 0x64006400u | (byte & 0xFu) | ((byte & 0xF0u) << 12);
          const half2v w2 = (__builtin_bit_cast(half2v, pq) - hz2) * hs2;
          wp[j] = __builtin_bit_cast(unsigned, w2);
        }
        *(uint4*)(&Bs[b_n][kr * 8]) = wv;
      }
    }

    __syncthreads();

    unsigned b0n, b1n, zpn;
    float scn;
    const int tn = (t + 1 < NT) ? (t + 1) : t;
    load_b(tn, b0n, b1n, zpn, scn);

    v8h af[4], bfr[4];
#pragma unroll
    for (int i = 0; i < 4; ++i) {
      af[i] = *(const v8h*)(&As[wm + i * 16 + lr][lk]);
      bfr[i] = *(const v8h*)(&Bs[wn + i * 16 + lr][lk]);
    }
#pragma unroll
    for (int mi = 0; mi < 4; ++mi) {
#pragma unroll
      for (int ni = 0; ni < 4; ++ni) {
        acc[mi][ni] = __builtin_amdgcn_mfma_f32_16x16x32_f16(
            af[mi], bfr[ni], acc[mi][ni], 0, 0, 0);
      }
    }

    __syncthreads();

    b0c = b0n; b1c = b1n; zpc = zpn; scc = scn;
  }

#pragma unroll
  for (int mi = 0; mi < 4; ++mi) {
#pragma unroll
    for (int ni = 0; ni < 4; ++ni) {
#pragma unroll
      for (int r = 0; r < 4; ++r) {
        const int row = m0 + wm + mi * 16 + (lane >> 4) * 4 + r;
        const int col = n0 + wn + ni * 16 + lr;
        out[(size_t)row * N + col] = acc[mi][ni][r];
      }
    }
  }
}

// ---------------- fallback 2: round-3 fully fused (128x128) ----------------
__global__ __launch_bounds__(256, 2)
void qgemm_fused(const float* __restrict__ x,
                 const unsigned* __restrict__ qweight,
                 const unsigned* __restrict__ qzeros,
                 const float* __restrict__ scales,
                 float* __restrict__ out, int M, int N, int K) {
  __shared__ short As[128][LDK];
  __shared__ short Bs[128][LDK];

  const int tid = threadIdx.x;
  const int lane = tid & 63;
  const int wid = tid >> 6;
  const int n0 = blockIdx.x * 128;
  const int m0 = blockIdx.y * 128;
  const int wm = (wid >> 1) * 64;
  const int wn = (wid & 1) * 64;
  const int lr = lane & 15;
  const int lk = (lane >> 4) * 8;

  const int a_row = tid >> 3;
  const int a_col = (tid & 7) * 4;
  const int b_n = tid & 127;
  const int b_kr0 = tid >> 7;
  const int gn = n0 + b_n;

  const float* xb = x + (size_t)(m0 + a_row) * K + a_col;
  const unsigned* qwb = qweight + (size_t)b_kr0 * N + gn;

  v4f acc[4][4] = {};
  const int NT = K / BK;

  float4 axc[4];
  unsigned b0c, b1c, zpc;
  float scc;

  auto load_step = [&](int t, float4 ax[4], unsigned& b0, unsigned& b1,
                       unsigned& zp, float& sc) {
    const int kk = t * BK;
#pragma unroll
    for (int p = 0; p < 4; ++p)
      ax[p] = *(const float4*)(xb + (size_t)(p * 32) * K + kk);
    const size_t qoff = (size_t)(kk >> 3) * N;
    b0 = qwb[qoff];
    b1 = qwb[qoff + 2 * (size_t)N];
    const int g = kk >> 7;
    zp = qzeros[(size_t)g * (N >> 3) + (gn >> 3)];
    sc = scales[(size_t)g * N + gn];
  };

  load_step(0, axc, b0c, b1c, zpc, scc);

#pragma unroll 2
  for (int t = 0; t < NT; ++t) {
    const unsigned z = (zpc >> ((gn & 7) * 4)) & 15u;
    const unsigned hz_u = 0x64006400u | z | (z << 16);
    const half2v hz2 = __builtin_bit_cast(half2v, hz_u);
    const half2v hs2 = __builtin_bit_cast(half2v, pkrtz_u32(scc, scc));

#pragma unroll
    for (int p = 0; p < 4; ++p) {
      const int row = p * 32 + a_row;
      uint2 pv;
      pv.x = pkrtz_u32(axc[p].x, axc[p].y);
      pv.y = pkrtz_u32(axc[p].z, axc[p].w);
      *(uint2*)(&As[row][a_col]) = pv;
    }
    {
      const unsigned qvs[2] = {b0c, b1c};
#pragma unroll
      for (int q = 0; q < 2; ++q) {
        const int kr = b_kr0 + q * 2;
        const unsigned qv = qvs[q];
        uint4 wv;
        unsigned* wp = (unsigned*)&wv;
#pragma unroll
        for (int j = 0; j < 4; ++j) {
          const unsigned byte = qv >> (8 * j);
          const unsigned pq = 0x64006400u | (byte & 0xFu) | ((byte & 0xF0u) << 12);
          const half2v w2 = (__builtin_bit_cast(half2v, pq) - hz2) * hs2;
          wp[j] = __builtin_bit_cast(unsigned, w2);
        }
        *(uint4*)(&Bs[b_n][kr * 8]) = wv;
      }
    }

    __syncthreads();

    float4 axn[4];
    unsigned b0n, b1n, zpn;
    float scn;
    const int tn = (t + 1 < NT) ? (t + 1) : t;
    load_step(tn, axn, b0n, b1n, zpn, scn);

    v8h af[4], bfr[4];
#pragma unroll
    for (int i = 0; i < 4; ++i) {
      af[i] = *(const v8h*)(&As[wm + i * 16 + lr][lk]);
      bfr[i] = *(const v8h*)(&Bs[wn + i * 16 + lr][lk]);
    }
#pragma unroll
    for (int mi = 0; mi < 4; ++mi) {
#pragma unroll
      for (int ni = 0; ni < 4; ++ni) {
        acc[mi][ni] = __builtin_amdgcn_mfma_f32_16x16x32_f16(
            af[mi], bfr[ni], acc[mi][ni], 0, 0, 0);
      }
    }

    __syncthreads();

#pragma unroll
    for (int p = 0; p < 4; ++p) axc[p] = axn[p];
    b0c = b0n; b1c = b1n; zpc = zpn; scc = scn;
  }

#pragma unroll
  for (int mi = 0; mi < 4; ++mi) {
#pragma unroll
    for (int ni = 0; ni < 4; ++ni) {
#pragma unroll
      for (int r = 0; r < 4; ++r) {
        const int row = m0 + wm + mi * 16 + (lane >> 4) * 4 + r;
        const int col = n0 + wn + ni * 16 + lr;
        out[(size_t)row * N + col] = acc[mi][ni][r];
      }
    }
  }
}

extern "C" void kernel_launch(void* const* d_in, const int* in_sizes, int n_in,
                              void* d_out, int out_size, void* d_ws, size_t ws_size,
                              hipStream_t stream) {
  const float* x = (const float*)d_in[0];
  const unsigned* qweight = (const unsigned*)d_in[1];
  const unsigned* qzeros = (const unsigned*)d_in[2];
  const float* scales = (const float*)d_in[3];
  float* out = (float*)d_out;

  const int K = 4096;
  const int N = 11008;
  const int M = in_sizes[0] / K;  // 4096

  const size_t A_BYTES = (size_t)(M / 128) * (K / 32) * TILE_BYTES;   // 41.9 MB
  const size_t W_BYTES = (size_t)(N / 256) * (K / 32) * WTILE_BYTES;  // 112.7 MB

  if (ws_size >= A_BYTES + W_BYTES) {
    unsigned short* xt = (unsigned short*)d_ws;
    unsigned short* wtp = (unsigned short*)((char*)d_ws + A_BYTES);
    prep_x<<<dim3(K / 32, M / 128), 320, 0, stream>>>(x, xt, K);
    prep_w<<<dim3(N / 256, K / 32), 256, 0, stream>>>(qweight, qzeros, scales, wtp, N, K);
    qgemm_pre<<<dim3(M / 128, N / 256), 512, 0, stream>>>(xt, wtp, out, M, N, K);
  } else if (ws_size >= A_BYTES) {
    unsigned short* xt = (unsigned short*)d_ws;
    prep_x<<<dim3(K / 32, M / 128), 320, 0, stream>>>(x, xt, K);
    qgemm_dma<<<dim3(N / 256, M / 128), 512, 0, stream>>>(xt, qweight, qzeros, scales,
                                                          out, M, N, K);
  } else {
    qgemm_fused<<<dim3(N / 128, M / 128), 256, 0, stream>>>(x, qweight, qzeros, scales,
                                                            out, M, N, K);
  }
}